// Round 5
// baseline (551.636 us; speedup 1.0000x reference)
//
#include <hip/hip_runtime.h>

typedef unsigned short u16;
typedef short short8 __attribute__((ext_vector_type(8)));
typedef float f32x4 __attribute__((ext_vector_type(4)));
typedef _Float16 f16;
typedef f16 f16x2 __attribute__((ext_vector_type(2)));
typedef f16 f16x4 __attribute__((ext_vector_type(4)));
typedef f16 f16x8 __attribute__((ext_vector_type(8)));

#define B_ 8
#define T_ 1024
#define E_ 1024
#define H_ 16
#define D_ 64
#define BH_ 128
#define RNNB 64      // RNN blocks, 2 chains each
#define PROJB 4096
#define WOB 16

__device__ __forceinline__ float ftanh(float x){
    x = fminf(8.0f, fmaxf(-8.0f, x));
    float e2 = __expf(2.0f * x);
    return 1.0f - 2.0f * __builtin_amdgcn_rcpf(e2 + 1.0f);
}

__device__ __forceinline__ u16 f2h(float x){
    union { f16 h; u16 u; } v; v.h = (f16)x; return v.u;
}

__device__ __forceinline__ float dot8(f16x8 a, f16x8 b, float acc){
#if __has_builtin(__builtin_amdgcn_fdot2)
    f16x2 a0 = {a[0],a[1]}, a1 = {a[2],a[3]}, a2 = {a[4],a[5]}, a3 = {a[6],a[7]};
    f16x2 b0 = {b[0],b[1]}, b1 = {b[2],b[3]}, b2 = {b[4],b[5]}, b3 = {b[6],b[7]};
    acc = __builtin_amdgcn_fdot2(a0, b0, acc, false);
    acc = __builtin_amdgcn_fdot2(a1, b1, acc, false);
    acc = __builtin_amdgcn_fdot2(a2, b2, acc, false);
    acc = __builtin_amdgcn_fdot2(a3, b3, acc, false);
#else
    #pragma unroll
    for (int i = 0; i < 8; ++i) acc += (float)a[i] * (float)b[i];
#endif
    return acc;
}

__device__ __forceinline__ f16x8 pack8(f32x4 a, f32x4 b){
    f16x8 r;
    r[0]=(f16)a[0]; r[1]=(f16)a[1]; r[2]=(f16)a[2]; r[3]=(f16)a[3];
    r[4]=(f16)b[0]; r[5]=(f16)b[1]; r[6]=(f16)b[2]; r[7]=(f16)b[3];
    return r;
}

// Opaque register pin (round-4 proven: kills remat-reload of loop-invariants).
#define PIN8(x) do { f32x4 _t = __builtin_bit_cast(f32x4, x); \
                     asm volatile("" : "+v"(_t));             \
                     x = __builtin_bit_cast(f16x8, _t); } while (0)

#define PACKM(M, wi, wh) \
    f16x8 M##0 = pack8(wi[0]+wh[0],   wi[1]+wh[1]);   \
    f16x8 M##1 = pack8(wi[2]+wh[2],   wi[3]+wh[3]);   \
    f16x8 M##2 = pack8(wi[4]+wh[4],   wi[5]+wh[5]);   \
    f16x8 M##3 = pack8(wi[6]+wh[6],   wi[7]+wh[7]);   \
    f16x8 M##4 = pack8(wi[8]+wh[8],   wi[9]+wh[9]);   \
    f16x8 M##5 = pack8(wi[10]+wh[10], wi[11]+wh[11]); \
    f16x8 M##6 = pack8(wi[12]+wh[12], wi[13]+wh[13]); \
    f16x8 M##7 = pack8(wi[14]+wh[14], wi[15]+wh[15]);

#define PACKN(N, wi) \
    f16x8 N##0 = pack8(wi[0],  wi[1]);  \
    f16x8 N##1 = pack8(wi[2],  wi[3]);  \
    f16x8 N##2 = pack8(wi[4],  wi[5]);  \
    f16x8 N##3 = pack8(wi[6],  wi[7]);  \
    f16x8 N##4 = pack8(wi[8],  wi[9]);  \
    f16x8 N##5 = pack8(wi[10], wi[11]); \
    f16x8 N##6 = pack8(wi[12], wi[13]); \
    f16x8 N##7 = pack8(wi[14], wi[15]);

#define LOADX(X, hp) \
    f16x8 X##0 = hp[0], X##1 = hp[1], X##2 = hp[2], X##3 = hp[3], \
          X##4 = hp[4], X##5 = hp[5], X##6 = hp[6], X##7 = hp[7];

#define DOT64(M, X, CC) \
    ( ((dot8(M##0,X##0,CC) + dot8(M##1,X##1,0.f)) +   \
       (dot8(M##2,X##2,0.f) + dot8(M##3,X##3,0.f))) + \
      ((dot8(M##4,X##4,0.f) + dot8(M##5,X##5,0.f)) +  \
       (dot8(M##6,X##6,0.f) + dot8(M##7,X##7,0.f))) )

// ---------------------------------------------------------------------------
// Kernel 1: RNN (blocks 0..63, 2 chains/wave interleaved so one chain's
// LDS write->read latency (~240 cyc, the round-4 507-cyc/step culprit) hides
// under the other's VALU) + q/v projection + Wo^T f16 conversion.
// ---------------------------------------------------------------------------
__global__ __launch_bounds__(256, 1) void proj_rnn_kernel(
    const float* __restrict__ src, const float* __restrict__ tgt,
    const float* __restrict__ Wq,  const float* __restrict__ Wv,
    const float* __restrict__ Wo,  const float* __restrict__ Wih,
    const float* __restrict__ Whh, const float* __restrict__ bih,
    const float* __restrict__ bhh,
    u16* __restrict__ qh, u16* __restrict__ vh, u16* __restrict__ nwh,
    u16* __restrict__ woT)
{
    int bid = blockIdx.x;
    if (bid < RNNB) {
        // ---- RNN role: single wave, 2 chains, no barriers ----
        if (threadIdx.x >= 64) return;
        __shared__ __align__(16) u16 hl[2][D_];
        const int e = threadIdx.x;
        const int c0 = bid * 2, c1 = c0 + 1;
        const int b0 = c0 >> 4, h0 = c0 & 15;
        const int b1 = c1 >> 4, h1 = c1 & 15;
        const f32x4* wiA = (const f32x4*)(Wih + ((size_t)h0 * D_ + e) * D_);
        const f32x4* whA = (const f32x4*)(Whh + ((size_t)h0 * D_ + e) * D_);
        const f32x4* wiB = (const f32x4*)(Wih + ((size_t)h1 * D_ + e) * D_);
        const f32x4* whB = (const f32x4*)(Whh + ((size_t)h1 * D_ + e) * D_);
        float cA = bih[h0 * D_ + e] + bhh[h0 * D_ + e];
        float cB = bih[h1 * D_ + e] + bhh[h1 * D_ + e];
        asm volatile("" : "+v"(cA));
        asm volatile("" : "+v"(cB));

        PACKM(mA, wiA, whA)
        PACKM(mB, wiB, whB)
        PIN8(mA0); PIN8(mA1); PIN8(mA2); PIN8(mA3);
        PIN8(mA4); PIN8(mA5); PIN8(mA6); PIN8(mA7);
        PIN8(mB0); PIN8(mB1); PIN8(mB2); PIN8(mB3);
        PIN8(mB4); PIN8(mB5); PIN8(mB6); PIN8(mB7);

        hl[0][e] = f2h(tgt[(size_t)b0 * T_ * E_ + h0 * D_ + e]);
        hl[1][e] = f2h(tgt[(size_t)b1 * T_ * E_ + h1 * D_ + e]);

        u16* npA = nwh + (size_t)c0 * T_ * D_;
        u16* npB = nwh + (size_t)c1 * T_ * D_;
        const f16x8* hA = (const f16x8*)hl[0];
        const f16x8* hB = (const f16x8*)hl[1];

        // step 1: h1 = tanh(Wih k0 + c)
        {
            PACKN(nA, wiA)
            LOADX(xA, hA)
            float hv = ftanh(DOT64(nA, xA, cA));
            u16 hb = f2h(hv); hl[0][e] = hb; npA[e] = hb;
        }
        {
            PACKN(nB, wiB)
            LOADX(xB, hB)
            float hv = ftanh(DOT64(nB, xB, cB));
            u16 hb = f2h(hv); hl[1][e] = hb; npB[e] = hb;
        }

        #pragma unroll 1
        for (int t = 1; t < T_; ++t) {
            LOADX(xA, hA)
            LOADX(xB, hB)
            float sA = DOT64(mA, xA, cA);
            float sB = DOT64(mB, xB, cB);
            float vA = ftanh(sA), vB = ftanh(sB);
            u16 ua = f2h(vA), ub = f2h(vB);
            hl[0][e] = ua; npA[(size_t)t * D_ + e] = ua;
            hl[1][e] = ub; npB[(size_t)t * D_ + e] = ub;
        }
    } else if (bid < RNNB + PROJB) {
        // ---- projection role (round-4 proven) ----
        int pb   = bid - RNNB;         // 0 .. 4095
        int bh   = pb >> 5;
        int tile = pb & 31;
        int b = bh >> 4, h = bh & 15;
        int e  = threadIdx.x & 63;
        int tg = threadIdx.x >> 6;
        int t0 = tile * 32 + tg * 8;

        const float* wq = Wq + (size_t)h * D_ * D_ + e;
        const float* wv = Wv + (size_t)h * D_ * D_ + e;
        const float* s0 = src + ((size_t)b * T_ + t0) * E_ + h * D_;
        const float* g0 = tgt + ((size_t)b * T_ + t0) * E_ + h * D_;

        float aq[8] = {0,0,0,0,0,0,0,0};
        float av[8] = {0,0,0,0,0,0,0,0};
        #pragma unroll 4
        for (int d4 = 0; d4 < 16; ++d4) {
            float q0 = wq[(4*d4+0)*64], q1 = wq[(4*d4+1)*64],
                  q2 = wq[(4*d4+2)*64], q3 = wq[(4*d4+3)*64];
            float v0 = wv[(4*d4+0)*64], v1 = wv[(4*d4+1)*64],
                  v2 = wv[(4*d4+2)*64], v3 = wv[(4*d4+3)*64];
            #pragma unroll
            for (int j = 0; j < 8; ++j) {
                float4 x = *(const float4*)(s0 + (size_t)j * E_ + 4*d4);
                float4 y = *(const float4*)(g0 + (size_t)j * E_ + 4*d4);
                aq[j] += x.x*q0 + x.y*q1 + x.z*q2 + x.w*q3;
                av[j] += y.x*v0 + y.y*v1 + y.z*v2 + y.w*v3;
            }
        }
        u16* qp = qh + ((size_t)bh * T_ + t0) * D_ + e;
        #pragma unroll
        for (int j = 0; j < 8; ++j) qp[(size_t)j * D_] = f2h(aq[j] * (1.0f/256.0f));
        f16x8 vv;
        #pragma unroll
        for (int j = 0; j < 8; ++j) vv[j] = (f16)av[j];
        *(f16x8*)(vh + ((size_t)bh * D_ + e) * T_ + t0) = vv;
    } else {
        // ---- Wo^T f16 conversion: woT[h][e][d] = Wo[h][d][e] ----
        int h = bid - (RNNB + PROJB);  // 0..15
        const float* wsrc = Wo + (size_t)h * 4096;
        u16* wdst = woT + (size_t)h * 4096;
        int d  = threadIdx.x & 63;
        int e0 = threadIdx.x >> 6;     // 0..3
        #pragma unroll
        for (int i = 0; i < 16; ++i) {
            int e = e0 * 16 + i;
            wdst[e * 64 + d] = f2h(wsrc[d * 64 + e]);  // coalesced writes
        }
    }
}

// ---------------------------------------------------------------------------
// Kernel 2: flash attention + fused Wo. NO __syncthreads anywhere.
// S^T trick: S^T = MFMA(A=K-frag, B=Q-frag) — C-layout gives each lane
// P values at fixed q=l15, 4 consecutive keys -> vectorized b64 P writes into
// a per-wave LDS buffer, b128 A-frag reads (same-wave in-order, no barrier).
// K/V fragments load directly from global (L2-resident; no LDS staging).
// l-reduction deferred to after the kt loop (no max -> sums factor out).
// Wave = 32 q rows (2 fragment sets); block = 4 independent waves.
// ---------------------------------------------------------------------------
#define MFMA16(a, b, c) __builtin_amdgcn_mfma_f32_16x16x32_f16(a, b, c, 0, 0, 0)

__global__ __launch_bounds__(256, 3) void attn_kernel(
    const u16* __restrict__ qh,   // [bh][t][64] f16, pre-scaled 1/256
    const u16* __restrict__ kh,   // nw states [bh][t][64] f16
    const u16* __restrict__ vh,   // V^T [bh][d][t] f16
    const u16* __restrict__ woT,  // Wo^T f16 [h][e][d]
    float* __restrict__ out)      // [B][T][E] fp32
{
    __shared__ __align__(16) u16 Pl[4][2][16 * 64];   // [wave][qf] 16 KB

    const int tid  = threadIdx.x;
    const int lane = tid & 63;
    const int w    = tid >> 6;
    const int l15  = lane & 15;
    const int quad = lane >> 4;
    const int sw   = lane & 7;
    const int bh   = blockIdx.x >> 3;
    const int qblk = blockIdx.x & 7;
    const int b    = bh >> 4, h = bh & 15;

    const size_t base  = (size_t)bh * T_ * D_;
    const size_t vbase = (size_t)bh * D_ * T_;
    const int qbase = qblk * 128 + w * 32;

    // Q fragments (B-operand for S^T): B[k=d][n=q]
    f16x8 aq[2][2];
    #pragma unroll
    for (int qf = 0; qf < 2; ++qf)
        #pragma unroll
        for (int kc = 0; kc < 2; ++kc)
            aq[qf][kc] = *(const f16x8*)(qh + base +
                (size_t)(qbase + qf*16 + l15) * 64 + kc*32 + quad*8);

    f32x4 oacc[2][4];
    #pragma unroll
    for (int qf = 0; qf < 2; ++qf)
        #pragma unroll
        for (int nt = 0; nt < 4; ++nt) oacc[qf][nt] = (f32x4){0.f,0.f,0.f,0.f};
    float lsum[2] = {0.f, 0.f};

    u16* P0 = Pl[w][0];
    u16* P1 = Pl[w][1];
    const f32x4 zf = {0.f, 0.f, 0.f, 0.f};

    #pragma unroll 1
    for (int kt = 0; kt < 16; ++kt) {
        // K A-fragments from global: A[m=key][k=d]
        const u16* kp = kh + base + (size_t)(kt * 64) * 64;
        f16x8 ka[4][2];
        #pragma unroll
        for (int u = 0; u < 4; ++u)
            #pragma unroll
            for (int kc = 0; kc < 2; ++kc)
                ka[u][kc] = *(const f16x8*)(kp + (16*u + l15)*64 + kc*32 + quad*8);

        // S^T = K·Q^T ; exp ; P -> per-wave LDS (b64, swizzled)
        #pragma unroll
        for (int qf = 0; qf < 2; ++qf) {
            u16* Pq = qf ? P1 : P0;
            #pragma unroll
            for (int u = 0; u < 4; ++u) {
                f32x4 st = MFMA16(ka[u][0], aq[qf][0], zf);
                st       = MFMA16(ka[u][1], aq[qf][1], st);
                float p0 = __expf(st[0]), p1 = __expf(st[1]),
                      p2 = __expf(st[2]), p3 = __expf(st[3]);
                lsum[qf] += (p0 + p1) + (p2 + p3);
                f16x4 pk = {(f16)p0, (f16)p1, (f16)p2, (f16)p3};
                int chunk = 2*u + (quad >> 1);          // keys (16u+quad*4)>>3
                *(f16x4*)&Pq[l15*64 + ((chunk ^ sw) * 8) + (quad & 1) * 4] = pk;
            }
        }

        // V B-fragments from global: B[k=key][n=d]
        f16x8 bv[4][2];
        #pragma unroll
        for (int nt = 0; nt < 4; ++nt)
            #pragma unroll
            for (int kc = 0; kc < 2; ++kc)
                bv[nt][kc] = *(const f16x8*)(vh + vbase +
                    (size_t)(16*nt + l15) * T_ + kt*64 + kc*32 + quad*8);

        // O += P·V  (P A-frags from per-wave LDS; same-wave in-order RAW)
        #pragma unroll
        for (int qf = 0; qf < 2; ++qf) {
            u16* Pq = qf ? P1 : P0;
            f16x8 ap0 = *(const f16x8*)&Pq[l15*64 + (((0 + quad) ^ sw) * 8)];
            f16x8 ap1 = *(const f16x8*)&Pq[l15*64 + (((4 + quad) ^ sw) * 8)];
            #pragma unroll
            for (int nt = 0; nt < 4; ++nt) {
                oacc[qf][nt] = MFMA16(ap0, bv[nt][0], oacc[qf][nt]);
                oacc[qf][nt] = MFMA16(ap1, bv[nt][1], oacc[qf][nt]);
            }
        }
    }

    // ---- l reduction (across quads) and broadcast to accumulator rows ----
    float rl[2][4];
    #pragma unroll
    for (int qf = 0; qf < 2; ++qf) {
        float l = lsum[qf];
        l += __shfl_xor(l, 16, 64);
        l += __shfl_xor(l, 32, 64);
        #pragma unroll
        for (int r = 0; r < 4; ++r)
            rl[qf][r] = __builtin_amdgcn_rcpf(__shfl(l, quad*4 + r, 64));
    }

    // ---- O (normalized, f16) -> per-wave LDS in A-layout; no barrier ----
    #pragma unroll
    for (int qf = 0; qf < 2; ++qf) {
        u16* Pq = qf ? P1 : P0;
        #pragma unroll
        for (int nt = 0; nt < 4; ++nt) {
            #pragma unroll
            for (int r = 0; r < 4; ++r) {
                int row = quad*4 + r, col = 16*nt + l15;
                Pq[row*64 + (((col >> 3) ^ (row & 7)) * 8) + (col & 7)] =
                    f2h(oacc[qf][nt][r] * rl[qf][r]);
            }
        }
    }

    // ---- out = O · Wo  (Wo^T B-frags straight from global/L2) ----
    f16x8 bw[4][2];
    #pragma unroll
    for (int nt = 0; nt < 4; ++nt)
        #pragma unroll
        for (int kc = 0; kc < 2; ++kc)
            bw[nt][kc] = *(const f16x8*)(woT + (size_t)h*4096 +
                (16*nt + l15)*64 + kc*32 + quad*8);

    #pragma unroll
    for (int qf = 0; qf < 2; ++qf) {
        u16* Pq = qf ? P1 : P0;
        f16x8 ao0 = *(const f16x8*)&Pq[l15*64 + (((0 + quad) ^ sw) * 8)];
        f16x8 ao1 = *(const f16x8*)&Pq[l15*64 + (((4 + quad) ^ sw) * 8)];
        #pragma unroll
        for (int nt = 0; nt < 4; ++nt) {
            f32x4 oo = MFMA16(ao0, bw[nt][0], zf);
            oo       = MFMA16(ao1, bw[nt][1], oo);
            #pragma unroll
            for (int r = 0; r < 4; ++r) {
                int qg = qbase + qf*16 + quad*4 + r;
                out[((size_t)b * T_ + qg) * E_ + h*64 + 16*nt + l15] = oo[r];
            }
        }
    }
}

// ---------------------------------------------------------------------------
extern "C" void kernel_launch(void* const* d_in, const int* in_sizes, int n_in,
                              void* d_out, int out_size, void* d_ws, size_t ws_size,
                              hipStream_t stream)
{
    const float* src = (const float*)d_in[0];
    const float* tgt = (const float*)d_in[1];
    const float* Wq  = (const float*)d_in[2];
    const float* Wv  = (const float*)d_in[3];
    const float* Wo  = (const float*)d_in[4];
    const float* Wih = (const float*)d_in[5];
    const float* Whh = (const float*)d_in[6];
    const float* bih = (const float*)d_in[7];
    const float* bhh = (const float*)d_in[8];
    float* out = (float*)d_out;

    char* ws = (char*)d_ws;
    u16* qh  = (u16*)(ws);                             // [bh][t][d] 16 MB
    u16* vh  = (u16*)(ws + (size_t)16 * 1024 * 1024);  // V^T [bh][d][t] 16 MB
    u16* nwh = (u16*)(ws + (size_t)32 * 1024 * 1024);  // [bh][t][d] 16 MB
    u16* woT = (u16*)(ws + (size_t)48 * 1024 * 1024);  // Wo^T f16 128 KB

    (void)in_sizes; (void)n_in; (void)out_size; (void)ws_size;

    proj_rnn_kernel<<<dim3(RNNB + PROJB + WOB), 256, 0, stream>>>(
        src, tgt, Wq, Wv, Wo, Wih, Whh, bih, bhh, qh, vh, nwh, woT);
    attn_kernel<<<dim3(8 * BH_), 256, 0, stream>>>(qh, nwh, vh, woT, out);
}